// Round 1
// baseline (101.438 us; speedup 1.0000x reference)
//
#include <hip/hip_runtime.h>

// Locally-connected 2d: x[32,16,66,66], weight[1,32,16,64,64,9], bias[1,32,64,64]
// out[32,32,64,64] fp32.
// Thread = (o, h, w); lane = w (coalesced). acc[32] over batch in registers so
// each weight element is fetched from HBM exactly once and reused 32x.

#define B_   32
#define CO_  32
#define CI_  16
#define H_   64
#define W_   64
#define XH_  66
#define XW_  66

__global__ __launch_bounds__(256) void lc2d_kernel(
    const float* __restrict__ x,
    const float* __restrict__ wt,
    const float* __restrict__ bias,
    float* __restrict__ out) {
  const int w  = threadIdx.x;                      // 0..63
  const int oh = blockIdx.x * 4 + threadIdx.y;     // 0..2047
  const int o  = oh >> 6;
  const int h  = oh & 63;

  float acc[B_];
#pragma unroll
  for (int b = 0; b < B_; ++b) acc[b] = 0.0f;

  // weight[0][o][c][h][w][k]: idx = (((o*CI + c)*H + h)*W + w)*9 + k
  const float* wp = wt + ((((size_t)o * CI_ + 0) * H_ + h) * W_ + w) * 9;
  const size_t w_cstride = (size_t)H_ * W_ * 9;    // 36864 floats per c

  // x[b][c][h+i][w+j]: idx = ((b*CI + c)*XH + h+i)*XW + (w+j)
  const float* xp0 = x + (size_t)h * XW_ + w;      // b=0, c=0
  const size_t x_cstride = (size_t)XH_ * XW_;      // 4356
  const size_t x_bstride = (size_t)CI_ * XH_ * XW_;// 69696

  for (int c = 0; c < CI_; ++c) {
    float wr[9];
#pragma unroll
    for (int k = 0; k < 9; ++k) wr[k] = wp[k];
    wp += w_cstride;

    const float* xb = xp0 + (size_t)c * x_cstride;
#pragma unroll
    for (int b = 0; b < B_; ++b) {
      float a = acc[b];
#pragma unroll
      for (int i = 0; i < 3; ++i) {
        const float* xr = xb + i * XW_;
        a = fmaf(wr[3 * i + 0], xr[0], a);
        a = fmaf(wr[3 * i + 1], xr[1], a);
        a = fmaf(wr[3 * i + 2], xr[2], a);
      }
      acc[b] = a;
      xb += x_bstride;
    }
  }

  const float bv = bias[((size_t)o * H_ + h) * W_ + w];
  float* op = out + ((size_t)o * H_ + h) * W_ + w; // b=0 slot
  const size_t o_bstride = (size_t)CO_ * H_ * W_;  // 131072
#pragma unroll
  for (int b = 0; b < B_; ++b) {
    op[(size_t)b * o_bstride] = acc[b] + bv;
  }
}

extern "C" void kernel_launch(void* const* d_in, const int* in_sizes, int n_in,
                              void* d_out, int out_size, void* d_ws, size_t ws_size,
                              hipStream_t stream) {
  const float* x    = (const float*)d_in[0];
  const float* wt   = (const float*)d_in[1];
  const float* bias = (const float*)d_in[2];
  float* out = (float*)d_out;

  dim3 block(64, 4, 1);
  dim3 grid((CO_ * H_) / 4, 1, 1);  // 2048 (o,h) pairs / 4 per block = 512
  lc2d_kernel<<<grid, block, 0, stream>>>(x, wt, bias, out);
}

// Round 3
// 66.233 us; speedup vs baseline: 1.5315x; 1.5315x over previous
//
#include <hip/hip_runtime.h>

// Locally-connected 2d: x[32,16,66,66], weight[1,32,16,64,64,9], bias[1,32,64,64]
// out[32,32,64,64] fp32.
//
// R2 structure (resubmit after infra failure): thread = (o-pair, h, w, b-group of 8).
// Per c-iter: 18 weight loads + 72 x loads -> 144 FMAs (load:FMA = 0.625).
// Block = 64x4, threadIdx.y = b-group -> all 4 waves share the block's weight
// slice (L1 reuse x4; weight fetched from L2/HBM exactly once per block).
// 1024 blocks = 4096 waves = 16 waves/CU. Bijective XCD swizzle keeps the 16
// opair-blocks sharing the same x rows on one XCD's L2.

#define B_   32
#define CO_  32
#define CI_  16
#define H_   64
#define W_   64
#define XH_  66
#define XW_  66

__global__ __launch_bounds__(256, 4) void lc2d_kernel(
    const float* __restrict__ x,
    const float* __restrict__ wt,
    const float* __restrict__ bias,
    float* __restrict__ out) {
  // 1024 blocks, 8 XCDs -> each XCD gets a contiguous 128-logical-block chunk.
  const int d = blockIdx.x;
  const int L = (d & 7) * 128 + (d >> 3);
  const int opair = L & 15;        // 16 o-pairs, innermost: x-sharing blocks adjacent
  const int h     = L >> 4;        // 64 h values
  const int w  = threadIdx.x;      // 0..63 (lane = w, coalesced)
  const int bg = threadIdx.y;      // 0..3 batch group
  const int o0 = opair * 2;
  const int b0 = bg * 8;

  float acc[2][8];
#pragma unroll
  for (int i = 0; i < 2; ++i)
#pragma unroll
    for (int b = 0; b < 8; ++b) acc[i][b] = 0.0f;

  // weight[0][o][c][h][w][k]: idx = (((o*CI + c)*H + h)*W + w)*9 + k
  const size_t w_cstride = (size_t)H_ * W_ * 9;        // 36864
  const size_t w_ostride = (size_t)CI_ * w_cstride;    // 589824
  const float* wp = wt + ((((size_t)o0 * CI_) * H_ + h) * W_ + w) * 9;

  // x[b][c][hh][ww]: idx = ((b*CI + c)*XH + hh)*XW + ww
  const size_t x_cstride = (size_t)XH_ * XW_;          // 4356
  const size_t x_bstride = (size_t)CI_ * x_cstride;    // 69696
  const float* xbase = x + (size_t)b0 * x_bstride + (size_t)h * XW_ + w;

  for (int c = 0; c < CI_; ++c) {
    float w0[9], w1[9];
    const float* wpc = wp + (size_t)c * w_cstride;
#pragma unroll
    for (int k = 0; k < 9; ++k) {
      w0[k] = wpc[k];
      w1[k] = wpc[w_ostride + k];
    }

    const float* xc = xbase + (size_t)c * x_cstride;
#pragma unroll
    for (int b = 0; b < 8; ++b) {
      const float* xb = xc + (size_t)b * x_bstride;
      float xv[9];
#pragma unroll
      for (int i = 0; i < 3; ++i) {
#pragma unroll
        for (int j = 0; j < 3; ++j) xv[3 * i + j] = xb[i * XW_ + j];
      }
#pragma unroll
      for (int k = 0; k < 9; ++k) {
        acc[0][b] = fmaf(w0[k], xv[k], acc[0][b]);
        acc[1][b] = fmaf(w1[k], xv[k], acc[1][b]);
      }
    }
  }

  const float bv0 = bias[((size_t)o0 * H_ + h) * W_ + w];
  const float bv1 = bias[((size_t)(o0 + 1) * H_ + h) * W_ + w];
  const size_t hw = (size_t)h * W_ + w;
#pragma unroll
  for (int b = 0; b < 8; ++b) {
    float* op = out + (((size_t)(b0 + b) * CO_ + o0) * H_ * W_) + hw;
    op[0]              = acc[0][b] + bv0;
    op[(size_t)H_ * W_] = acc[1][b] + bv1;
  }
}

extern "C" void kernel_launch(void* const* d_in, const int* in_sizes, int n_in,
                              void* d_out, int out_size, void* d_ws, size_t ws_size,
                              hipStream_t stream) {
  const float* x    = (const float*)d_in[0];
  const float* wt   = (const float*)d_in[1];
  const float* bias = (const float*)d_in[2];
  float* out = (float*)d_out;

  dim3 block(64, 4, 1);
  dim3 grid(1024, 1, 1);  // 16 opairs * 64 h
  lc2d_kernel<<<grid, block, 0, stream>>>(x, wt, bias, out);
}

// Round 4
// 59.821 us; speedup vs baseline: 1.6957x; 1.1072x over previous
//
#include <hip/hip_runtime.h>

// Locally-connected 2d: x[32,16,66,66], weight[1,32,16,64,64,9], bias[1,32,64,64]
// out[32,32,64,64] fp32.
//
// R4: same (o-pair, h, w, b-group) decomposition as R3, but weights are staged
// through LDS. R3's weight loads had 36 B/lane stride (36 cache lines per wave
// instruction, re-touched 9x) -> memory-path bound (VALUBusy 19%). Now the
// block cooperatively loads the 16 weight rows (2 o x 8 c, 576 contiguous
// floats each) as coalesced float4, and lanes read their 9 weights from LDS
// (stride-9 dwords: bank permutation, 2-way aliasing = free).
// LDS = 36 KB -> 4 blocks/CU (144 KB of 160). 2 stages cover c=0..15.

#define B_   32
#define CO_  32
#define CI_  16
#define H_   64
#define W_   64
#define XH_  66
#define XW_  66
#define CSTG 8                 // c's per LDS stage
#define ROWS (2 * CSTG)        // 16 rows (2 o x 8 c)
#define ROWF (W_ * 9)          // 576 floats per row

__global__ __launch_bounds__(256, 4) void lc2d_kernel(
    const float* __restrict__ x,
    const float* __restrict__ wt,
    const float* __restrict__ bias,
    float* __restrict__ out) {
  __shared__ float wlds[ROWS * ROWF];  // 9216 floats = 36 KB

  // 1024 blocks, 8 XCDs -> bijective swizzle, contiguous 128-block chunks.
  const int d = blockIdx.x;
  const int L = (d & 7) * 128 + (d >> 3);
  const int opair = L & 15;        // innermost: x-sharing blocks adjacent
  const int h     = L >> 4;
  const int w   = threadIdx.x;     // 0..63 (lane = w)
  const int bg  = threadIdx.y;     // 0..3 batch group
  const int tid = bg * 64 + w;     // 0..255
  const int o0 = opair * 2;
  const int b0 = bg * 8;

  float acc[2][8];
#pragma unroll
  for (int i = 0; i < 2; ++i)
#pragma unroll
    for (int b = 0; b < 8; ++b) acc[i][b] = 0.0f;

  const size_t x_cstride = (size_t)XH_ * XW_;           // 4356
  const size_t x_bstride = (size_t)CI_ * x_cstride;     // 69696
  const float* xbase = x + (size_t)b0 * x_bstride + (size_t)h * XW_ + w;

  const size_t w_cstride = (size_t)H_ * W_ * 9;         // 36864 floats
  const size_t w_ostride = (size_t)CI_ * w_cstride;     // 589824 floats

  for (int s = 0; s < 2; ++s) {
    const int c0 = s * CSTG;
    __syncthreads();  // stage s=1 must not overwrite rows still being read

    // Cooperative stage: 16 rows x 144 float4 = 2304 float4; 9 per thread.
    // Row r = o*8+cc; global row base is 16-B aligned (2304 B rows).
#pragma unroll
    for (int i = 0; i < 9; ++i) {
      const int f4 = tid + i * 256;        // 0..2303
      const int r = f4 / 144;              // magic-mul
      const int within = f4 - r * 144;
      const int o = r >> 3, cc = r & 7;
      const float4* src = (const float4*)(
          wt + (((size_t)(o0 + o) * CI_ + (c0 + cc)) * H_ + h) * (size_t)(W_ * 9)) + within;
      *((float4*)&wlds[(size_t)r * ROWF] + within) = *src;
    }
    __syncthreads();

    for (int cc = 0; cc < CSTG; ++cc) {
      const int c = c0 + cc;
      float w0[9], w1[9];
      const float* l0 = &wlds[(size_t)cc * ROWF + w * 9];
      const float* l1 = &wlds[(size_t)(CSTG + cc) * ROWF + w * 9];
#pragma unroll
      for (int k = 0; k < 9; ++k) {
        w0[k] = l0[k];
        w1[k] = l1[k];
      }

      const float* xc = xbase + (size_t)c * x_cstride;
#pragma unroll
      for (int b = 0; b < 8; ++b) {
        const float* xb = xc + (size_t)b * x_bstride;
        float xv[9];
#pragma unroll
        for (int i = 0; i < 3; ++i) {
#pragma unroll
          for (int j = 0; j < 3; ++j) xv[3 * i + j] = xb[i * XW_ + j];
        }
#pragma unroll
        for (int k = 0; k < 9; ++k) {
          acc[0][b] = fmaf(w0[k], xv[k], acc[0][b]);
          acc[1][b] = fmaf(w1[k], xv[k], acc[1][b]);
        }
      }
    }
  }

  const float bv0 = bias[((size_t)o0 * H_ + h) * W_ + w];
  const float bv1 = bias[((size_t)(o0 + 1) * H_ + h) * W_ + w];
  const size_t hw = (size_t)h * W_ + w;
#pragma unroll
  for (int b = 0; b < 8; ++b) {
    float* op = out + (((size_t)(b0 + b) * CO_ + o0) * H_ * W_) + hw;
    op[0]               = acc[0][b] + bv0;
    op[(size_t)H_ * W_] = acc[1][b] + bv1;
  }
}

extern "C" void kernel_launch(void* const* d_in, const int* in_sizes, int n_in,
                              void* d_out, int out_size, void* d_ws, size_t ws_size,
                              hipStream_t stream) {
  const float* x    = (const float*)d_in[0];
  const float* wt   = (const float*)d_in[1];
  const float* bias = (const float*)d_in[2];
  float* out = (float*)d_out;

  dim3 block(64, 4, 1);
  dim3 grid(1024, 1, 1);  // 16 opairs * 64 h
  lc2d_kernel<<<grid, block, 0, stream>>>(x, wt, bias, out);
}